// Round 1
// baseline (2197.116 us; speedup 1.0000x reference)
//
#include <hip/hip_runtime.h>

#define N_PTS  16384
#define B_SZ   8
#define NGROUP 1024
#define KNN_K  32
#define ATTR   7

// d_out layout (floats), reference return order:
// neighborhood (8,1024,32,7), center_idx (8,1024), centroids_attrs (8,1024,7), centroids_coors (8,1024,3)
#define OFF_NB     0
#define OFF_IDX    (B_SZ * NGROUP * KNN_K * ATTR)            // 1835008
#define OFF_CATTR  (OFF_IDX + B_SZ * NGROUP)                 // 1843200
#define OFF_CCOORD (OFF_CATTR + B_SZ * NGROUP * ATTR)        // 1900544

typedef float v2f __attribute__((ext_vector_type(2)));                 // packed-f32 math
typedef float f2u __attribute__((ext_vector_type(2), aligned(4)));     // 4B-aligned vec load

// ---------------------------------------------------------------------------
// Kernel 0: prep — x2[b][n] = sum_a xyz[b][n][a]^2 (sequential, no FMA) and
// SoA transpose xt[b][a][n] for coalesced KNN reads.
// ---------------------------------------------------------------------------
__global__ void prep_kernel(const float* __restrict__ xyz, float* __restrict__ x2,
                            float* __restrict__ xt) {
#pragma clang fp contract(off)
    int i = blockIdx.x * blockDim.x + threadIdx.x;
    if (i >= B_SZ * N_PTS) return;
    const int b = i >> 14;
    const int p = i & (N_PTS - 1);
    const float* q = xyz + (size_t)i * ATTR;
    f2u a01 = *(const f2u*)q;
    f2u a23 = *(const f2u*)(q + 2);
    f2u a45 = *(const f2u*)(q + 4);
    float a6 = q[6];
    float s = a01.x * a01.x;
    s = s + a01.y * a01.y;
    s = s + a23.x * a23.x;
    s = s + a23.y * a23.y;
    s = s + a45.x * a45.x;
    s = s + a45.y * a45.y;
    s = s + a6 * a6;
    x2[i] = s;
    float* T = xt + (size_t)b * ATTR * N_PTS + p;
    T[0 * N_PTS] = a01.x;
    T[1 * N_PTS] = a01.y;
    T[2 * N_PTS] = a23.x;
    T[3 * N_PTS] = a23.y;
    T[4 * N_PTS] = a45.x;
    T[5 * N_PTS] = a45.y;
    T[6 * N_PTS] = a6;
}

// ---------------------------------------------------------------------------
// Kernel 1: farthest point sampling. One 1024-thread block per batch,
// 16 points/thread in registers as float2 pairs (packed v_pk_* fp32 math).
// Per step: ONE barrier. Reduction via monotone u64 key (d-bits<<32 |
// (16384-idx)) -> wave butterfly max -> lane-0 atomicMax into a
// triple-buffered LDS slot (reset is barrier-ordered) -> broadcast read.
// Winner coords re-fetched via uniform (scalar) global load — no 2nd barrier.
// ---------------------------------------------------------------------------
__global__ __launch_bounds__(1024) void fps_kernel(const float* __restrict__ xyz,
                                                   float* __restrict__ out) {
#pragma clang fp contract(off)
    const int b = blockIdx.x;
    const int t = threadIdx.x;
    const int lane = t & 63;
    const float* X = xyz + (size_t)b * N_PTS * ATTR;

    v2f px[8], py[8], pz[8], pd[8];
#pragma unroll
    for (int j = 0; j < 8; ++j) {
        const int p0 = t + (j << 11);              // t + (2j)*1024
        const float* q0 = X + (size_t)p0 * ATTR;
        const float* q1 = q0 + (size_t)1024 * ATTR;
        f2u u0 = *(const f2u*)q0; float z0 = q0[2];
        f2u u1 = *(const f2u*)q1; float z1 = q1[2];
        px[j] = (v2f){u0.x, u1.x};
        py[j] = (v2f){u0.y, u1.y};
        pz[j] = (v2f){z0, z1};
        pd[j] = (v2f){1e10f, 1e10f};
    }

    __shared__ unsigned long long slot[3];
    __shared__ int sel[NGROUP];
    if (t == 0) { slot[0] = 0ull; sel[0] = 0; }
    float cx = X[0], cy = X[1], cz = X[2];        // farthest=0 initial centroid
    __syncthreads();

    for (int s = 0; s < NGROUP - 1; ++s) {
        const v2f cx2 = {cx, cx}, cy2 = {cy, cy}, cz2 = {cz, cz};
        // update distances + thread-local argmax.
        // strict '>' with ascending point index == np.argmax first-max-wins.
        float best = -1.0f;
        int   bidx = 0;
#pragma unroll
        for (int j = 0; j < 8; ++j) {
            v2f dx = px[j] - cx2;                 // v_pk_add (neg)
            v2f dy = py[j] - cy2;
            v2f dz = pz[j] - cz2;
            v2f a  = dx * dx;                     // v_pk_mul
            a = a + dy * dy;                      // (dx^2+dy^2) — unfused
            a = a + dz * dz;                      // + dz^2 — sequential
            v2f nd;
            nd.x = fminf(pd[j].x, a.x);
            nd.y = fminf(pd[j].y, a.y);
            pd[j] = nd;
            if (nd.x > best) { best = nd.x; bidx = t + ((2 * j) << 10); }
            if (nd.y > best) { best = nd.y; bidx = t + ((2 * j + 1) << 10); }
        }
        // monotone key: larger d wins; tie -> smaller index (larger 16384-idx).
        // d >= 0 always, so float bits are order-preserving as u32.
        unsigned long long key =
            ((unsigned long long)__float_as_uint(best) << 32) |
            (unsigned)(N_PTS - bidx);
#pragma unroll
        for (int off = 1; off < 64; off <<= 1) {
            unsigned long long ok = __shfl_xor(key, off);
            if (ok > key) key = ok;
        }
        if (lane == 0) atomicMax(&slot[s % 3], key);
        // reset the NEXT step's slot now: reads of this slot happened at step
        // s-2 (before barrier s-1); next step's atomics happen after barrier s.
        if (t == 0) slot[(s + 1) % 3] = 0ull;
        __syncthreads();
        key = slot[s % 3];
        const int lo = (int)(unsigned)key;
        bidx = N_PTS - __builtin_amdgcn_readfirstlane(lo);
        if (t == 0) sel[s + 1] = bidx;
        // uniform (SGPR) address -> scalar load of winner coords, L2-hit.
        const float* q = X + (size_t)bidx * ATTR;
        cx = q[0]; cy = q[1]; cz = q[2];
    }
    __syncthreads();

    // outputs: center_idx, centroids_attrs, centroids_coors (1024 threads = 1024 groups)
    {
        const int g = t;
        const int idx = sel[g];
        const float* q = X + (size_t)idx * ATTR;
        float a0 = q[0], a1 = q[1], a2 = q[2], a3 = q[3], a4 = q[4], a5 = q[5], a6 = q[6];
        out[OFF_IDX + b * NGROUP + g] = (float)idx;
        float* ca = out + OFF_CATTR + (size_t)(b * NGROUP + g) * ATTR;
        ca[0] = a0; ca[1] = a1; ca[2] = a2; ca[3] = a3; ca[4] = a4; ca[5] = a5; ca[6] = a6;
        float* cc = out + OFF_CCOORD + (size_t)(b * NGROUP + g) * 3;
        cc[0] = a0; cc[1] = a1; cc[2] = a2;
    }
}

// ---------------------------------------------------------------------------
// distributed top-32 insert (sorted list lives one-slot-per-lane, lanes 0..31)
// ---------------------------------------------------------------------------
__device__ __forceinline__ void topk_insert(float d2, int p, int lane,
                                            float& ld, int& li, float& kd, int& ki) {
    const bool cand = (d2 < kd) || (d2 == kd && p < ki);
    unsigned long long mask = __ballot(cand);
    while (mask) {
        const int l = __ffsll(mask) - 1;
        mask &= mask - 1;
        const float dc = __shfl(d2, l);
        const int   pc = __shfl(p, l);
        if ((dc < kd) || (dc == kd && pc < ki)) {
            const bool before = (ld < dc) || (ld == dc && li < pc);
            const int pos = (int)__popcll(__ballot(before));
            const float sd = __shfl_up(ld, 1);
            const int   si = __shfl_up(li, 1);
            if (lane == pos)      { ld = dc; li = pc; }
            else if (lane > pos)  { ld = sd; li = si; }
            if (lane >= KNN_K)    { ld = __builtin_inff(); li = 0x7fffffff; }
            kd = __shfl(ld, KNN_K - 1);
            ki = __shfl(li, KNN_K - 1);
        }
    }
}

// ---------------------------------------------------------------------------
// Kernel 2: 32-NN in 7-D + gather/recenter. One wave per group.
// SoA path: 7+1 coalesced dword loads per 64-point batch (28 line-touches
// vs 196 for AoS). d2 = (c2 + x2) - 2*dot, sums sequential & unfused.
// ---------------------------------------------------------------------------
__global__ __launch_bounds__(256) void knn_kernel(const float* __restrict__ xyz,
                                                  const float* __restrict__ x2,
                                                  const float* __restrict__ xt,
                                                  float* __restrict__ out) {
#pragma clang fp contract(off)
    const int lane = threadIdx.x & 63;
    const int gg = blockIdx.x * 4 + (threadIdx.x >> 6);   // global group 0..8191
    const int b  = gg >> 10;
    const float* X = xyz + (size_t)b * N_PTS * ATTR;

    const float* C = out + OFF_CATTR + (size_t)gg * ATTR;
    const float c0 = C[0], c1 = C[1], c2a = C[2], c3 = C[3], c4 = C[4], c5 = C[5], c6 = C[6];
    float csq = c0 * c0;
    csq = csq + c1 * c1;
    csq = csq + c2a * c2a;
    csq = csq + c3 * c3;
    csq = csq + c4 * c4;
    csq = csq + c5 * c5;
    csq = csq + c6 * c6;

    float ld = __builtin_inff();
    int   li = 0x7fffffff;
    float kd = __builtin_inff();
    int   ki = 0x7fffffff;

    if (xt != nullptr) {
        const float* T0 = xt + (size_t)b * ATTR * N_PTS;
        const float* T1 = T0 + N_PTS;
        const float* T2 = T1 + N_PTS;
        const float* T3 = T2 + N_PTS;
        const float* T4 = T3 + N_PTS;
        const float* T5 = T4 + N_PTS;
        const float* T6 = T5 + N_PTS;
        const float* XB = x2 + (size_t)b * N_PTS;
        for (int p0 = 0; p0 < N_PTS; p0 += 64) {
            const int p = p0 + lane;
            const float q0 = T0[p], q1 = T1[p], q2 = T2[p], q3 = T3[p];
            const float q4 = T4[p], q5 = T5[p], q6 = T6[p];
            float dot = c0 * q0;
            dot = dot + c1 * q1;
            dot = dot + c2a * q2;
            dot = dot + c3 * q3;
            dot = dot + c4 * q4;
            dot = dot + c5 * q5;
            dot = dot + c6 * q6;
            const float xx = XB[p];
            const float d2 = (csq + xx) - 2.0f * dot;
            topk_insert(d2, p, lane, ld, li, kd, ki);
        }
    } else {
        for (int p0 = 0; p0 < N_PTS; p0 += 64) {
            const int p = p0 + lane;
            const float* q = X + (size_t)p * ATTR;
            float dot = c0 * q[0];
            dot = dot + c1 * q[1];
            dot = dot + c2a * q[2];
            dot = dot + c3 * q[3];
            dot = dot + c4 * q[4];
            dot = dot + c5 * q[5];
            dot = dot + c6 * q[6];
            float xx = q[0] * q[0];
            xx = xx + q[1] * q[1];
            xx = xx + q[2] * q[2];
            xx = xx + q[3] * q[3];
            xx = xx + q[4] * q[4];
            xx = xx + q[5] * q[5];
            xx = xx + q[6] * q[6];
            const float d2 = (csq + xx) - 2.0f * dot;
            topk_insert(d2, p, lane, ld, li, kd, ki);
        }
    }

    // neighborhood output: lane j writes rank-j neighbor (ascending (d2,idx))
    if (lane < KNN_K) {
        const float* q = X + (size_t)li * ATTR;
        float* o = out + OFF_NB + ((size_t)gg * KNN_K + lane) * ATTR;
        o[0] = q[0] - c0;
        o[1] = q[1] - c1;
        o[2] = q[2] - c2a;
        o[3] = q[3];
        o[4] = q[4];
        o[5] = q[5];
        o[6] = q[6];
    }
}

extern "C" void kernel_launch(void* const* d_in, const int* in_sizes, int n_in,
                              void* d_out, int out_size, void* d_ws, size_t ws_size,
                              hipStream_t stream) {
    const float* xyz = (const float*)d_in[0];
    float* out = (float*)d_out;

    const size_t need = (size_t)(B_SZ * N_PTS) * (1 + ATTR) * sizeof(float);  // 4 MiB
    const bool use_ws = ws_size >= need;
    float* x2 = use_ws ? (float*)d_ws : nullptr;
    float* xt = use_ws ? ((float*)d_ws + B_SZ * N_PTS) : nullptr;

    if (use_ws) {
        prep_kernel<<<(B_SZ * N_PTS + 255) / 256, 256, 0, stream>>>(xyz, x2, xt);
    }
    fps_kernel<<<B_SZ, 1024, 0, stream>>>(xyz, out);
    knn_kernel<<<(B_SZ * NGROUP) / 4, 256, 0, stream>>>(xyz, x2, xt, out);
}

// Round 2
// 1997.884 us; speedup vs baseline: 1.0997x; 1.0997x over previous
//
#include <hip/hip_runtime.h>

#define N_PTS  16384
#define B_SZ   8
#define NGROUP 1024
#define KNN_K  32
#define ATTR   7

// d_out layout (floats), reference return order:
// neighborhood (8,1024,32,7), center_idx (8,1024), centroids_attrs (8,1024,7), centroids_coors (8,1024,3)
#define OFF_NB     0
#define OFF_IDX    (B_SZ * NGROUP * KNN_K * ATTR)            // 1835008
#define OFF_CATTR  (OFF_IDX + B_SZ * NGROUP)                 // 1843200
#define OFF_CCOORD (OFF_CATTR + B_SZ * NGROUP * ATTR)        // 1900544

typedef float v2f __attribute__((ext_vector_type(2)));                 // packed-f32 math
typedef float f2u __attribute__((ext_vector_type(2), aligned(4)));     // 4B-aligned vec load

// ---------------------------------------------------------------------------
// DPP 64-lane reductions (VALU-only; no DS-pipe traffic).
// row_shr:1/2/4/8 then row_bcast15/31 leaves the full-wave result in lane 63.
// bound_ctrl=false + old=src makes invalid source lanes a no-op (identity).
// ---------------------------------------------------------------------------
template <int CTRL>
__device__ __forceinline__ float fmax_dpp_step(float x) {
    int d = __builtin_amdgcn_update_dpp(__float_as_int(x), __float_as_int(x),
                                        CTRL, 0xf, 0xf, false);
    return fmaxf(x, __int_as_float(d));
}
template <int CTRL>
__device__ __forceinline__ unsigned umin_dpp_step(unsigned x) {
    unsigned d = (unsigned)__builtin_amdgcn_update_dpp((int)x, (int)x,
                                                       CTRL, 0xf, 0xf, false);
    return x < d ? x : d;
}

__device__ __forceinline__ float wave_max_f32(float x) {
    x = fmax_dpp_step<0x111>(x);   // row_shr:1
    x = fmax_dpp_step<0x112>(x);   // row_shr:2
    x = fmax_dpp_step<0x114>(x);   // row_shr:4
    x = fmax_dpp_step<0x118>(x);   // row_shr:8  -> row max in lane 15/31/47/63
    x = fmax_dpp_step<0x142>(x);   // row_bcast15 -> lane31=max[0..31], lane63=max[32..63]
    x = fmax_dpp_step<0x143>(x);   // row_bcast31 -> lane63=max[0..63]
    return __int_as_float(__builtin_amdgcn_readlane(__float_as_int(x), 63));
}
__device__ __forceinline__ unsigned wave_min_u32(unsigned x) {
    x = umin_dpp_step<0x111>(x);
    x = umin_dpp_step<0x112>(x);
    x = umin_dpp_step<0x114>(x);
    x = umin_dpp_step<0x118>(x);
    x = umin_dpp_step<0x142>(x);
    x = umin_dpp_step<0x143>(x);
    return (unsigned)__builtin_amdgcn_readlane((int)x, 63);
}

// ---------------------------------------------------------------------------
// Kernel 0: prep — x2[b][n] = sum_a xyz[b][n][a]^2 (sequential, no FMA) and
// SoA transpose xt[b][a][n] for coalesced KNN reads.
// ---------------------------------------------------------------------------
__global__ void prep_kernel(const float* __restrict__ xyz, float* __restrict__ x2,
                            float* __restrict__ xt) {
#pragma clang fp contract(off)
    int i = blockIdx.x * blockDim.x + threadIdx.x;
    if (i >= B_SZ * N_PTS) return;
    const int b = i >> 14;
    const int p = i & (N_PTS - 1);
    const float* q = xyz + (size_t)i * ATTR;
    f2u a01 = *(const f2u*)q;
    f2u a23 = *(const f2u*)(q + 2);
    f2u a45 = *(const f2u*)(q + 4);
    float a6 = q[6];
    float s = a01.x * a01.x;
    s = s + a01.y * a01.y;
    s = s + a23.x * a23.x;
    s = s + a23.y * a23.y;
    s = s + a45.x * a45.x;
    s = s + a45.y * a45.y;
    s = s + a6 * a6;
    x2[i] = s;
    float* T = xt + (size_t)b * ATTR * N_PTS + p;
    T[0 * N_PTS] = a01.x;
    T[1 * N_PTS] = a01.y;
    T[2 * N_PTS] = a23.x;
    T[3 * N_PTS] = a23.y;
    T[4 * N_PTS] = a45.x;
    T[5 * N_PTS] = a45.y;
    T[6 * N_PTS] = a6;
}

// ---------------------------------------------------------------------------
// Kernel 1: farthest point sampling. One 512-thread block per batch,
// 32 points/thread held in REGISTERS as float2 pairs (v_pk_* fp32 math).
// __launch_bounds__(512,2) -> 256-VGPR cap; 4 arrays x 16 v2f = 128 VGPR of
// point data fits (round-1 counters showed the 1024-thread version spilled:
// VGPR_Count=40, 1.8 GB scratch FETCH per dispatch).
// Per step, one barrier:
//   per-thread packed distance update + local argmax (strict '>', ascending
//   point index == np.argmax first-max-wins)
//   -> DPP float-max wave reduce + DPP u32-min index reduce (no DS pipe)
//   -> lane0 writes u64 key (d-bits<<32 | (16384-idx)) to parity-buffered
//      LDS slot -> barrier -> all threads combine 8 slots (broadcast reads)
//   -> winner coords via uniform (scalar) global load, L2-resident.
// ---------------------------------------------------------------------------
__global__ __launch_bounds__(512, 2) void fps_kernel(const float* __restrict__ xyz,
                                                     float* __restrict__ out) {
#pragma clang fp contract(off)
    const int b = blockIdx.x;
    const int t = threadIdx.x;
    const int lane = t & 63;
    const int w = t >> 6;                      // wave 0..7
    const float* X = xyz + (size_t)b * N_PTS * ATTR;

    v2f px[16], py[16], pz[16], pd[16];
#pragma unroll
    for (int j = 0; j < 16; ++j) {
        const int p0 = t + (j << 10);          // t + (2j)*512
        const float* q0 = X + (size_t)p0 * ATTR;
        const float* q1 = q0 + (size_t)512 * ATTR;
        f2u u0 = *(const f2u*)q0; float z0 = q0[2];
        f2u u1 = *(const f2u*)q1; float z1 = q1[2];
        px[j] = (v2f){u0.x, u1.x};
        py[j] = (v2f){u0.y, u1.y};
        pz[j] = (v2f){z0, z1};
        pd[j] = (v2f){1e10f, 1e10f};
    }

    __shared__ unsigned long long sbuf[2][8];
    __shared__ int sel[NGROUP];
    if (t == 0) sel[0] = 0;
    float cx = X[0], cy = X[1], cz = X[2];     // farthest=0 initial centroid
    __syncthreads();

    for (int s = 0; s < NGROUP - 1; ++s) {
        const int par = s & 1;
        const v2f cx2 = {cx, cx}, cy2 = {cy, cy}, cz2 = {cz, cz};
        float best = -1.0f;
        int   bidx = 0;
#pragma unroll
        for (int j = 0; j < 16; ++j) {
            v2f dx = px[j] - cx2;              // v_pk_add (neg)
            v2f dy = py[j] - cy2;
            v2f dz = pz[j] - cz2;
            v2f a  = dx * dx;                  // v_pk_mul
            a = a + dy * dy;                   // (dx^2+dy^2) — unfused
            a = a + dz * dz;                   // + dz^2 — sequential
            v2f nd;
            nd.x = fminf(pd[j].x, a.x);
            nd.y = fminf(pd[j].y, a.y);
            pd[j] = nd;
            if (nd.x > best) { best = nd.x; bidx = t + ((2 * j) << 9); }
            if (nd.y > best) { best = nd.y; bidx = t + ((2 * j + 1) << 9); }
        }
        // wave-level: max distance, then smallest point index among exact ties.
        const float wm = wave_max_f32(best);
        const unsigned cand = (best == wm) ? (unsigned)bidx : 0xFFFFFFFFu;
        const unsigned widx = wave_min_u32(cand);
        if (lane == 0) {
            // d >= 0 so float bits are order-preserving as u32.
            sbuf[par][w] = ((unsigned long long)__float_as_uint(wm) << 32) |
                           (unsigned)(N_PTS - widx);
        }
        __syncthreads();
        // every thread combines the 8 wave keys (uniform broadcast reads).
        unsigned long long bk = sbuf[par][0];
#pragma unroll
        for (int i = 1; i < 8; ++i) {
            const unsigned long long k = sbuf[par][i];
            if (k > bk) bk = k;
        }
        const int win = N_PTS - (int)(unsigned)bk;
        const int sbidx = __builtin_amdgcn_readfirstlane(win);
        if (t == 0) sel[s + 1] = sbidx;
        // uniform (SGPR) address -> scalar load of winner coords, L2-hit.
        const float* q = X + (size_t)sbidx * ATTR;
        cx = q[0]; cy = q[1]; cz = q[2];
    }
    __syncthreads();

    // outputs: center_idx, centroids_attrs, centroids_coors (1024 groups, 512 threads)
    for (int g = t; g < NGROUP; g += 512) {
        const int idx = sel[g];
        const float* q = X + (size_t)idx * ATTR;
        float a0 = q[0], a1 = q[1], a2 = q[2], a3 = q[3], a4 = q[4], a5 = q[5], a6 = q[6];
        out[OFF_IDX + b * NGROUP + g] = (float)idx;
        float* ca = out + OFF_CATTR + (size_t)(b * NGROUP + g) * ATTR;
        ca[0] = a0; ca[1] = a1; ca[2] = a2; ca[3] = a3; ca[4] = a4; ca[5] = a5; ca[6] = a6;
        float* cc = out + OFF_CCOORD + (size_t)(b * NGROUP + g) * 3;
        cc[0] = a0; cc[1] = a1; cc[2] = a2;
    }
}

// ---------------------------------------------------------------------------
// distributed top-32 insert (sorted list lives one-slot-per-lane, lanes 0..31)
// ---------------------------------------------------------------------------
__device__ __forceinline__ void topk_insert(float d2, int p, int lane,
                                            float& ld, int& li, float& kd, int& ki) {
    const bool cand = (d2 < kd) || (d2 == kd && p < ki);
    unsigned long long mask = __ballot(cand);
    while (mask) {
        const int l = __ffsll(mask) - 1;
        mask &= mask - 1;
        const float dc = __shfl(d2, l);
        const int   pc = __shfl(p, l);
        if ((dc < kd) || (dc == kd && pc < ki)) {
            const bool before = (ld < dc) || (ld == dc && li < pc);
            const int pos = (int)__popcll(__ballot(before));
            const float sd = __shfl_up(ld, 1);
            const int   si = __shfl_up(li, 1);
            if (lane == pos)      { ld = dc; li = pc; }
            else if (lane > pos)  { ld = sd; li = si; }
            if (lane >= KNN_K)    { ld = __builtin_inff(); li = 0x7fffffff; }
            kd = __shfl(ld, KNN_K - 1);
            ki = __shfl(li, KNN_K - 1);
        }
    }
}

// ---------------------------------------------------------------------------
// Kernel 2: 32-NN in 7-D + gather/recenter. One wave per group.
// SoA path: 7+1 coalesced dword loads per 64-point batch (28 line-touches
// vs 196 for AoS). d2 = (c2 + x2) - 2*dot, sums sequential & unfused.
// ---------------------------------------------------------------------------
__global__ __launch_bounds__(256) void knn_kernel(const float* __restrict__ xyz,
                                                  const float* __restrict__ x2,
                                                  const float* __restrict__ xt,
                                                  float* __restrict__ out) {
#pragma clang fp contract(off)
    const int lane = threadIdx.x & 63;
    const int gg = blockIdx.x * 4 + (threadIdx.x >> 6);   // global group 0..8191
    const int b  = gg >> 10;
    const float* X = xyz + (size_t)b * N_PTS * ATTR;

    const float* C = out + OFF_CATTR + (size_t)gg * ATTR;
    const float c0 = C[0], c1 = C[1], c2a = C[2], c3 = C[3], c4 = C[4], c5 = C[5], c6 = C[6];
    float csq = c0 * c0;
    csq = csq + c1 * c1;
    csq = csq + c2a * c2a;
    csq = csq + c3 * c3;
    csq = csq + c4 * c4;
    csq = csq + c5 * c5;
    csq = csq + c6 * c6;

    float ld = __builtin_inff();
    int   li = 0x7fffffff;
    float kd = __builtin_inff();
    int   ki = 0x7fffffff;

    if (xt != nullptr) {
        const float* T0 = xt + (size_t)b * ATTR * N_PTS;
        const float* T1 = T0 + N_PTS;
        const float* T2 = T1 + N_PTS;
        const float* T3 = T2 + N_PTS;
        const float* T4 = T3 + N_PTS;
        const float* T5 = T4 + N_PTS;
        const float* T6 = T5 + N_PTS;
        const float* XB = x2 + (size_t)b * N_PTS;
        for (int p0 = 0; p0 < N_PTS; p0 += 64) {
            const int p = p0 + lane;
            const float q0 = T0[p], q1 = T1[p], q2 = T2[p], q3 = T3[p];
            const float q4 = T4[p], q5 = T5[p], q6 = T6[p];
            float dot = c0 * q0;
            dot = dot + c1 * q1;
            dot = dot + c2a * q2;
            dot = dot + c3 * q3;
            dot = dot + c4 * q4;
            dot = dot + c5 * q5;
            dot = dot + c6 * q6;
            const float xx = XB[p];
            const float d2 = (csq + xx) - 2.0f * dot;
            topk_insert(d2, p, lane, ld, li, kd, ki);
        }
    } else {
        for (int p0 = 0; p0 < N_PTS; p0 += 64) {
            const int p = p0 + lane;
            const float* q = X + (size_t)p * ATTR;
            float dot = c0 * q[0];
            dot = dot + c1 * q[1];
            dot = dot + c2a * q[2];
            dot = dot + c3 * q[3];
            dot = dot + c4 * q[4];
            dot = dot + c5 * q[5];
            dot = dot + c6 * q[6];
            float xx = q[0] * q[0];
            xx = xx + q[1] * q[1];
            xx = xx + q[2] * q[2];
            xx = xx + q[3] * q[3];
            xx = xx + q[4] * q[4];
            xx = xx + q[5] * q[5];
            xx = xx + q[6] * q[6];
            const float d2 = (csq + xx) - 2.0f * dot;
            topk_insert(d2, p, lane, ld, li, kd, ki);
        }
    }

    // neighborhood output: lane j writes rank-j neighbor (ascending (d2,idx))
    if (lane < KNN_K) {
        const float* q = X + (size_t)li * ATTR;
        float* o = out + OFF_NB + ((size_t)gg * KNN_K + lane) * ATTR;
        o[0] = q[0] - c0;
        o[1] = q[1] - c1;
        o[2] = q[2] - c2a;
        o[3] = q[3];
        o[4] = q[4];
        o[5] = q[5];
        o[6] = q[6];
    }
}

extern "C" void kernel_launch(void* const* d_in, const int* in_sizes, int n_in,
                              void* d_out, int out_size, void* d_ws, size_t ws_size,
                              hipStream_t stream) {
    const float* xyz = (const float*)d_in[0];
    float* out = (float*)d_out;

    const size_t need = (size_t)(B_SZ * N_PTS) * (1 + ATTR) * sizeof(float);  // 4 MiB
    const bool use_ws = ws_size >= need;
    float* x2 = use_ws ? (float*)d_ws : nullptr;
    float* xt = use_ws ? ((float*)d_ws + B_SZ * N_PTS) : nullptr;

    if (use_ws) {
        prep_kernel<<<(B_SZ * N_PTS + 255) / 256, 256, 0, stream>>>(xyz, x2, xt);
    }
    fps_kernel<<<B_SZ, 512, 0, stream>>>(xyz, out);
    knn_kernel<<<(B_SZ * NGROUP) / 4, 256, 0, stream>>>(xyz, x2, xt, out);
}